// Round 17
// baseline (663.851 us; speedup 1.0000x reference)
//
#include <hip/hip_runtime.h>
#include <hip/hip_bf16.h>

// Problem dims (fixed by reference)
#define BATCH 16384
#define TT    64
#define INF   48
#define FF    32
#define TFD   2048   // T*F   (GEMM1 K)
#define THD   8192   // T*H   (GEMM1 N)

typedef __attribute__((ext_vector_type(8))) short bf16x8;
typedef __attribute__((ext_vector_type(4))) short short4v;
typedef __attribute__((ext_vector_type(4))) float f32x4;
typedef __attribute__((ext_vector_type(16))) float f32x16;

#define SCHED __builtin_amdgcn_sched_barrier(0)
#define VMW(n) asm volatile("s_waitcnt vmcnt(" #n ")" ::: "memory")
#define LGKM0  asm volatile("s_waitcnt lgkmcnt(0)" ::: "memory")

__device__ inline void gload_lds16(const void* g, void* l) {
  __builtin_amdgcn_global_load_lds((const __attribute__((address_space(1))) void*)g,
                                   (__attribute__((address_space(3))) void*)l, 16, 0, 0);
}

__device__ inline f32x16 mfma32(bf16x8 a, bf16x8 b, f32x16 c) {
  return __builtin_amdgcn_mfma_f32_32x32x16_bf16(a, b, c, 0, 0, 0);
}

__device__ inline short f32_to_bf16_bits(float x) {
  __hip_bfloat16 h = __float2bfloat16(x);
  return *reinterpret_cast<short*>(&h);
}

__device__ inline unsigned packbf(float a, float b) {
  return ((unsigned)(unsigned short)f32_to_bf16_bits(b) << 16) |
         (unsigned)(unsigned short)f32_to_bf16_bits(a);
}

// ---------------- prep kernels ----------------

// xsf2: K16-granular fragment-linear X for 32x32x16 B-frags.
// Chunk (g32, u16, lane): elem j = bf16( x[g32*32 + (l&31)][t=u16>>1][sidx[f]] )
// with f = 16*(u16&1) + 8*(l>>5) + j  (i.e. global k = u16*16 + (l>>5)*8 + j).
__global__ void gather_cast_frag(const float* __restrict__ x, const int* __restrict__ sidx,
                                 __hip_bfloat16* __restrict__ xsf) {
  __shared__ int sx[FF];
  if (threadIdx.x < FF) sx[threadIdx.x] = sidx[threadIdx.x];
  __syncthreads();
  const int g32 = blockIdx.x;               // 0..511
  for (int it = 0; it < 32; ++it) {
    const int slot = it * 256 + threadIdx.x;   // 0..8191 = u16*64 + l
    const int u16 = slot >> 6;
    const int l   = slot & 63;
    const int lo  = l & 31, hi = l >> 5;
    const int t   = u16 >> 1;
    const int fb  = ((u16 & 1) << 4) + (hi << 3);
    const float* rp = x + ((size_t)(g32 * 32 + lo) * TT + t) * INF;
    bf16x8 v;
    #pragma unroll
    for (int j = 0; j < 8; ++j) v[j] = f32_to_bf16_bits(rp[sx[fb + j]]);
    *(bf16x8*)(xsf + ((size_t)g32 * 8192 + slot) * 8) = v;
  }
}

// W1t[n][k] = bf16(W1[k][n]);  W1: [TFD][THD] row-major. ushort4 stores.
__global__ void transpose_w1(const float* __restrict__ W1, __hip_bfloat16* __restrict__ W1t) {
  __shared__ float tile[64][65];
  const int k0 = blockIdx.x * 64;
  const int n0 = blockIdx.y * 64;
  const int tx = threadIdx.x & 63, ty = threadIdx.x >> 6;
  for (int r = ty; r < 64; r += 4)
    tile[r][tx] = W1[(size_t)(k0 + r) * THD + n0 + tx];
  __syncthreads();
  const int rn = threadIdx.x >> 4;          // 0..15
  const int kq = (threadIdx.x & 15) * 4;    // k-quad
  for (int rr = rn; rr < 64; rr += 16) {
    short4v v;
    #pragma unroll
    for (int i = 0; i < 4; ++i) v[i] = f32_to_bf16_bits(tile[kq + i][rr]);
    *(short4v*)(W1t + (size_t)(n0 + rr) * TFD + k0 + kq) = v;
  }
}

// w2t[f][n] = bf16( sum_t W2[n][t*32+f]*weight[t][f] );  beff[f] = bias[f] + sum_t b2[t*32+f]*weight[t][f]
__global__ void make_w2eff(const float* __restrict__ W2, const float* __restrict__ b2,
                           const float* __restrict__ weight, const float* __restrict__ bias,
                           __hip_bfloat16* __restrict__ w2t, float* __restrict__ beff) {
  const int n = blockIdx.x * 8 + (threadIdx.x >> 5);
  const int f = threadIdx.x & 31;
  const float* wr = W2 + (size_t)n * TFD;
  float s = 0.f;
  #pragma unroll 8
  for (int t = 0; t < TT; ++t) s += wr[t * FF + f] * weight[t * FF + f];
  w2t[(size_t)f * THD + n] = __float2bfloat16(s);
  if (blockIdx.x == 0 && threadIdx.x < FF) {
    float sb = bias[f];
    for (int t = 0; t < TT; ++t) sb += b2[t * FF + f] * weight[t * FF + f];
    beff[f] = sb;
  }
}

// ---------------- main fused GEMM ----------------
// r17 = r16 schedule (flattened 256-iter v-loop, 8x16KB W bufs staged 3
// ahead, X parity regs refilled 2 ahead, VMW 6/4/0, barrier every 2nd v,
// setprio) with 32x32x16 MFMA (m119: 8.07 vs 4.85 cyc -> MFMA pipe/iter
// 1242->1033 cyc). Frag layouts: A/B row|col=l&31, k=(l>>5)*8+j (direct
// analog of the verified 16x16x32 pattern). W LDS: per 32-row group (2KB)
// chunk c=R*4+kc stored at (q=c>>3, p=(c&7)^(q&7)) -> uniform 8 lanes per
// 16B slot (b128-optimal); staged linear-dest + inverse-mapped source.
// GEMM2 also 32x32x16 (f=32 = one tile); D-layout row=(r&3)+8*(r>>2)+4hi
// requires lane-half exchange -> 16B/lane LDS scratch bounce in dead buf 3
// (per-wave wid*2048 region, lgkm0+sched_barrier pinned; no cross-wave
// collision since stage regions are wid-partitioned).
// vmcnt ledger IDENTICAL to r16 (S=2, R=4 per iter).

__device__ inline void stage_w32(char* buf, const __hip_bfloat16* __restrict__ w1t,
                                 int n0, int k0, int wid, int l) {
  const int e = l >> 3;                      // 0..7
  const int p = l & 7;
  #pragma unroll
  for (int j = 0; j < 2; ++j) {
    const int q  = j * 8 + e;                // dest row-octet within 2KB group
    const int c  = q * 8 + (p ^ e);          // logical chunk (q&7 == e)
    const int R  = c >> 2, kc = c & 3;
    const __hip_bfloat16* g = w1t + (size_t)(n0 + wid * 32 + R) * TFD + k0 + kc * 8;
    gload_lds16(g, buf + wid * 2048 + j * 1024);  // wave-uniform; HW adds lane*16
  }
}

__device__ __forceinline__ void k_iter(char* lds, int v, int strip,
    const char* __restrict__ xb0, const char* __restrict__ xb1,
    const __hip_bfloat16* __restrict__ w1t,
    f32x16 (&acc)[4][2], bf16x8 (&xfu)[4],
    int gbase, int rdo0, int rdo1, int wid, int l, bool do_bar) {
  if (v <= 252) {
    const int vs = v + 3;
    stage_w32(lds + (size_t)(vs & 7) * 16384, w1t,
              strip * 1024 + (vs >> 6) * 256, (vs & 63) * 32, wid, l);
  }
  SCHED;
  const char* buf = lds + (size_t)(v & 7) * 16384 + gbase;
  #pragma unroll
  for (int nt = 0; nt < 4; ++nt) {
    const bf16x8 w0  = *(const bf16x8*)(buf + nt * 2048 + rdo0);
    const bf16x8 w1f = *(const bf16x8*)(buf + nt * 2048 + rdo1);
    __builtin_amdgcn_s_setprio(1);
    acc[nt][0] = mfma32(w0,  xfu[0], acc[nt][0]);
    acc[nt][0] = mfma32(w1f, xfu[1], acc[nt][0]);
    acc[nt][1] = mfma32(w0,  xfu[2], acc[nt][1]);
    acc[nt][1] = mfma32(w1f, xfu[3], acc[nt][1]);
    __builtin_amdgcn_s_setprio(0);
  }
  if (v <= 253) {   // refill the JUST-CONSUMED set with X tile (v+2) (cyclical over s)
    const int u = (v + 2) & 63;
    xfu[0] = *(const bf16x8*)(xb0 + (u * 2 + 0) * 1024);
    xfu[1] = *(const bf16x8*)(xb0 + (u * 2 + 1) * 1024);
    xfu[2] = *(const bf16x8*)(xb1 + (u * 2 + 0) * 1024);
    xfu[3] = *(const bf16x8*)(xb1 + (u * 2 + 1) * 1024);
  }
  SCHED;
  if (v <= 252)      { VMW(6); }
  else if (v == 253) { VMW(4); }
  else               { VMW(0); }
  SCHED;
  if (do_bar) {
    __builtin_amdgcn_s_barrier(); SCHED;
  }
}

__global__ __launch_bounds__(512, 2) void gemm_fused(
    const __hip_bfloat16* __restrict__ xsf,   // K16 fragment-linear X
    const __hip_bfloat16* __restrict__ w1t,   // [THD][TFD]
    const float* __restrict__ b1,             // [THD]
    const __hip_bfloat16* __restrict__ w2t,   // [FF][THD] bf16
    float* __restrict__ partial)              // [8][BATCH][FF]
{
  __shared__ __align__(16) char lds[131072];  // 8 x 16KB W buffers
  const int tid = threadIdx.x;
  const int wid = tid >> 6, l = tid & 63;
  const int mq = wid >> 2, bq = wid & 3;      // wave: n_w1-half (2) x batch-quarter (4)
  const int lo = l & 31, hi = l >> 5;
  const int strip = blockIdx.x & 7;           // strip == XCD -> W slice L2-resident
  const int bt = blockIdx.x >> 3;
  const int b0 = bt * 256;

  // W read offsets within a 2KB group (lane-constant): c = lo*4 + h2*2 + hi
  int rdo0, rdo1;
  {
    const int c0 = (lo << 2) + hi;       const int q0 = c0 >> 3;
    rdo0 = (q0 << 7) + ((((c0 & 7) ^ (q0 & 7))) << 4);
    const int c1 = c0 + 2;               const int q1 = c1 >> 3;
    rdo1 = (q1 << 7) + ((((c1 & 7) ^ (q1 & 7))) << 4);
  }
  const int gbase = mq << 13;                 // mq*4 groups * 2048B

  // X bases: wave's two 32-row batch groups (g32 = bt*8 + bq*2 + btile)
  const char* xb0 = (const char*)xsf + (size_t)(bt * 8 + bq * 2) * 131072 + l * 16;
  const char* xb1 = xb0 + 131072;

  const f32x16 vzero = {0.f,0.f,0.f,0.f,0.f,0.f,0.f,0.f,0.f,0.f,0.f,0.f,0.f,0.f,0.f,0.f};

  f32x16 acc2[2];                             // emb^T: one 32x32 tile per batch-32 group
  acc2[0] = vzero; acc2[1] = vzero;

  f32x16 acc[4][2];                           // h^T: [n-tile32][batch-tile32]
  #pragma unroll
  for (int nt = 0; nt < 4; ++nt) { acc[nt][0] = vzero; acc[nt][1] = vzero; }

  bf16x8 xfA[4], xfB[4];
  // ---- prologue (ONCE): S0, rA<-t0, S1, rB<-t1, S2; VMW(8) drains S0+rA ----
  stage_w32(lds, w1t, strip * 1024, 0, wid, l);
  SCHED;
  xfA[0] = *(const bf16x8*)(xb0 + 0);    xfA[1] = *(const bf16x8*)(xb0 + 1024);
  xfA[2] = *(const bf16x8*)(xb1 + 0);    xfA[3] = *(const bf16x8*)(xb1 + 1024);
  SCHED;
  stage_w32(lds + 16384, w1t, strip * 1024, 32, wid, l);
  SCHED;
  xfB[0] = *(const bf16x8*)(xb0 + 2048); xfB[1] = *(const bf16x8*)(xb0 + 3072);
  xfB[2] = *(const bf16x8*)(xb1 + 2048); xfB[3] = *(const bf16x8*)(xb1 + 3072);
  SCHED;
  stage_w32(lds + 32768, w1t, strip * 1024, 64, wid, l);
  SCHED;
  VMW(8); SCHED;
  __builtin_amdgcn_s_barrier(); SCHED;

  for (int vv = 0; vv < 256; vv += 2) {
    k_iter(lds, vv,     strip, xb0, xb1, w1t, acc, xfA, gbase, rdo0, rdo1, wid, l, false);
    k_iter(lds, vv + 1, strip, xb0, xb1, w1t, acc, xfB, gbase, rdo0, rdo1, wid, l, true);

    if ((vv & 63) == 62) {
      // ---- epilogue for s = vv>>6: bias+relu+pack, half-exchange, GEMM2 ----
      // Dead-buffer-3 scratch: per-wave wid*2048 region (stage regions are
      // wid-partitioned, so other waves' next stages can't collide).
      const int n0e = strip * 1024 + (vv >> 6) * 256;
      char* scr        = lds + 3 * 16384 + wid * 2048 + l * 16;
      const char* pscr = lds + 3 * 16384 + wid * 2048 + ((l ^ 32) * 16) + (hi ? 8 : 0);
      #pragma unroll
      for (int nt = 0; nt < 4; ++nt) {
        const int nb = n0e + (mq << 7) + (nt << 5);
        #pragma unroll
        for (int hh = 0; hh < 2; ++hh) {
          const bf16x8 af = *(const bf16x8*)(w2t + (size_t)lo * THD + nb + hh * 16 + (hi << 3));
          const float4 bv0 = *(const float4*)(b1 + nb + hh * 16 + (hi << 2));
          const float4 bv1 = *(const float4*)(b1 + nb + hh * 16 + 8 + (hi << 2));
          #pragma unroll
          for (int btl = 0; btl < 2; ++btl) {
            float r0 = acc[nt][btl][hh * 8 + 0] + bv0.x; r0 = r0 > 0.f ? r0 : 0.f;
            float r1 = acc[nt][btl][hh * 8 + 1] + bv0.y; r1 = r1 > 0.f ? r1 : 0.f;
            float r2 = acc[nt][btl][hh * 8 + 2] + bv0.z; r2 = r2 > 0.f ? r2 : 0.f;
            float r3 = acc[nt][btl][hh * 8 + 3] + bv0.w; r3 = r3 > 0.f ? r3 : 0.f;
            float r4 = acc[nt][btl][hh * 8 + 4] + bv1.x; r4 = r4 > 0.f ? r4 : 0.f;
            float r5 = acc[nt][btl][hh * 8 + 5] + bv1.y; r5 = r5 > 0.f ? r5 : 0.f;
            float r6 = acc[nt][btl][hh * 8 + 6] + bv1.z; r6 = r6 > 0.f ? r6 : 0.f;
            float r7 = acc[nt][btl][hh * 8 + 7] + bv1.w; r7 = r7 > 0.f ? r7 : 0.f;
            const unsigned a0 = packbf(r0, r1), a1 = packbf(r2, r3);
            const unsigned c0 = packbf(r4, r5), c1 = packbf(r6, r7);
            uint4 own; own.x = a0; own.y = a1; own.z = c0; own.w = c1;
            SCHED;
            *(uint4*)scr = own;
            LGKM0; SCHED;
            const uint2 pw = *(const uint2*)pscr;
            LGKM0; SCHED;
            uint4 fr;
            if (hi == 0) { fr.x = a0;   fr.y = a1;   fr.z = pw.x; fr.w = pw.y; }
            else         { fr.x = pw.x; fr.y = pw.y; fr.z = c0;   fr.w = c1;   }
            const bf16x8 hf = *reinterpret_cast<const bf16x8*>(&fr);
            acc2[btl] = mfma32(af, hf, acc2[btl]);
            SCHED;
          }
        }
        acc[nt][0] = vzero; acc[nt][1] = vzero;
      }
    }
  }

  // ---- merge the two mq-halves via LDS, then store ----
  float* sm = (float*)lds;                    // [256][32] f32 (32KB; buffers dead)
  __syncthreads();                            // all K-loop LDS traffic retired
  if (mq == 1) {
    #pragma unroll
    for (int btl = 0; btl < 2; ++btl) {
      const int row = (bq << 6) + (btl << 5) + lo;
      #pragma unroll
      for (int q = 0; q < 4; ++q) {
        f32x4 qv = { acc2[btl][q * 4 + 0], acc2[btl][q * 4 + 1],
                     acc2[btl][q * 4 + 2], acc2[btl][q * 4 + 3] };
        *(f32x4*)(sm + row * 32 + (q << 3) + (hi << 2)) = qv;
      }
    }
  }
  __syncthreads();
  if (mq == 0) {
    #pragma unroll
    for (int btl = 0; btl < 2; ++btl) {
      const int row = (bq << 6) + (btl << 5) + lo;
      #pragma unroll
      for (int q = 0; q < 4; ++q) {
        f32x4 qv = { acc2[btl][q * 4 + 0], acc2[btl][q * 4 + 1],
                     acc2[btl][q * 4 + 2], acc2[btl][q * 4 + 3] };
        qv = qv + *(const f32x4*)(sm + row * 32 + (q << 3) + (hi << 2));
        *(f32x4*)(partial + ((size_t)strip * BATCH + b0 + row) * FF + (q << 3) + (hi << 2)) = qv;
      }
    }
  }
}

// out[b][f] = beff[f] + sum_c partial[c][b][f]
__global__ void reduce_partial(const float* __restrict__ partial, const float* __restrict__ beff,
                               float* __restrict__ out) {
  const int idx = blockIdx.x * 256 + threadIdx.x;
  float s = beff[idx & 31];
  #pragma unroll
  for (int c = 0; c < 8; ++c) s += partial[(size_t)c * BATCH * FF + idx];
  out[idx] = s;
}

// ---------------- launch ----------------

extern "C" void kernel_launch(void* const* d_in, const int* in_sizes, int n_in,
                              void* d_out, int out_size, void* d_ws, size_t ws_size,
                              hipStream_t stream) {
  const float* x      = (const float*)d_in[0];
  const float* W1     = (const float*)d_in[1];
  const float* b1     = (const float*)d_in[2];
  const float* W2     = (const float*)d_in[3];
  const float* b2     = (const float*)d_in[4];
  const float* weight = (const float*)d_in[5];
  const float* bias   = (const float*)d_in[6];
  const int*   sidx   = (const int*)d_in[7];

  char* ws = (char*)d_ws;
  // ws layout (bytes):
  //   xsf     [512 g32][131072B]  bf16 : 0 .. 67108864
  //   w1t     [8192][2048]  bf16 :  67108864 .. 100663296
  //   w2t     [32][8192]    bf16 : 100663296 .. 101187584
  //   beff    [32]          f32  : 101187584 .. 101187712
  //   partial [8][16384][32] f32 : 101188608 .. 117965824
  __hip_bfloat16* xsf  = (__hip_bfloat16*)ws;
  __hip_bfloat16* w1t  = (__hip_bfloat16*)(ws + 67108864);
  __hip_bfloat16* w2t  = (__hip_bfloat16*)(ws + 100663296);
  float*          beff = (float*)(ws + 101187584);
  float*          part = (float*)(ws + 101188608);

  hipLaunchKernelGGL(gather_cast_frag, dim3(512), dim3(256), 0, stream, x, sidx, xsf);
  hipLaunchKernelGGL(transpose_w1, dim3(32, 128), dim3(256), 0, stream, W1, w1t);
  hipLaunchKernelGGL(make_w2eff,   dim3(1024),    dim3(256), 0, stream, W2, b2, weight, bias, w2t, beff);
  hipLaunchKernelGGL(gemm_fused,   dim3(512),     dim3(512), 0, stream, xsf, w1t, b1, w2t, part);
  hipLaunchKernelGGL(reduce_partial, dim3(2048),  dim3(256), 0, stream, part, beff, (float*)d_out);
}

// Round 18
// 597.441 us; speedup vs baseline: 1.1112x; 1.1112x over previous
//
#include <hip/hip_runtime.h>
#include <hip/hip_bf16.h>

// Problem dims (fixed by reference)
#define BATCH 16384
#define TT    64
#define INF   48
#define FF    32
#define TFD   2048   // T*F   (GEMM1 K)
#define THD   8192   // T*H   (GEMM1 N)

typedef __attribute__((ext_vector_type(8))) short bf16x8;
typedef __attribute__((ext_vector_type(4))) short bf16x4;
typedef __attribute__((ext_vector_type(4))) short short4v;
typedef __attribute__((ext_vector_type(4))) float f32x4;

#define SCHED __builtin_amdgcn_sched_barrier(0)
#define VMW(n) asm volatile("s_waitcnt vmcnt(" #n ")" ::: "memory")

__device__ inline void gload_lds16(const void* g, void* l) {
  __builtin_amdgcn_global_load_lds((const __attribute__((address_space(1))) void*)g,
                                   (__attribute__((address_space(3))) void*)l, 16, 0, 0);
}

__device__ inline f32x4 mfma16x16x16_bf16(bf16x4 a, bf16x4 b, f32x4 c) {
#if __has_builtin(__builtin_amdgcn_mfma_f32_16x16x16bf16_1k)
  return __builtin_amdgcn_mfma_f32_16x16x16bf16_1k(a, b, c, 0, 0, 0);
#else
  asm("v_mfma_f32_16x16x16_bf16 %0, %1, %2, %0" : "+v"(c) : "v"(a), "v"(b));
  return c;
#endif
}

__device__ inline short f32_to_bf16_bits(float x) {
  __hip_bfloat16 h = __float2bfloat16(x);
  return *reinterpret_cast<short*>(&h);
}

// ---------------- prep kernels ----------------

// xsf: fragment-linear X. Slot (g64, t, bi, lane):
//   element j: bf16( x[g64*64 + bi*16 + (lane&15)][t][sidx[(lane>>4)*8 + j]] )
__global__ void gather_cast_frag(const float* __restrict__ x, const int* __restrict__ sidx,
                                 __hip_bfloat16* __restrict__ xsf) {
  __shared__ int sx[FF];
  if (threadIdx.x < FF) sx[threadIdx.x] = sidx[threadIdx.x];
  __syncthreads();
  const int b64 = blockIdx.x >> 2;          // 0..255
  const int tq  = blockIdx.x & 3;           // t-quarter
  for (int it = 0; it < 16; ++it) {
    const int slot = (tq * 16 + it) * 256 + threadIdx.x;   // ((t*4+bi)*64+l)
    const int t  = slot >> 8;
    const int bi = (slot >> 6) & 3;
    const int l  = slot & 63;
    const int lo = l & 15, hi = l >> 4;
    const int row = b64 * 64 + bi * 16 + lo;
    const float* rp = x + ((size_t)row * TT + t) * INF;
    bf16x8 v;
    #pragma unroll
    for (int j = 0; j < 8; ++j) v[j] = f32_to_bf16_bits(rp[sx[hi * 8 + j]]);
    *(bf16x8*)(xsf + ((size_t)b64 * 16384 + slot) * 8) = v;
  }
}

// W1t[n][k] = bf16(W1[k][n]);  W1: [TFD][THD] row-major. ushort4 stores.
__global__ void transpose_w1(const float* __restrict__ W1, __hip_bfloat16* __restrict__ W1t) {
  __shared__ float tile[64][65];
  const int k0 = blockIdx.x * 64;
  const int n0 = blockIdx.y * 64;
  const int tx = threadIdx.x & 63, ty = threadIdx.x >> 6;
  for (int r = ty; r < 64; r += 4)
    tile[r][tx] = W1[(size_t)(k0 + r) * THD + n0 + tx];
  __syncthreads();
  const int rn = threadIdx.x >> 4;          // 0..15
  const int kq = (threadIdx.x & 15) * 4;    // k-quad
  for (int rr = rn; rr < 64; rr += 16) {
    short4v v;
    #pragma unroll
    for (int i = 0; i < 4; ++i) v[i] = f32_to_bf16_bits(tile[kq + i][rr]);
    *(short4v*)(W1t + (size_t)(n0 + rr) * TFD + k0 + kq) = v;
  }
}

// w2t[f][n] = bf16( sum_t W2[n][t*32+f]*weight[t][f] );  beff[f] = bias[f] + sum_t b2[t*32+f]*weight[t][f]
__global__ void make_w2eff(const float* __restrict__ W2, const float* __restrict__ b2,
                           const float* __restrict__ weight, const float* __restrict__ bias,
                           __hip_bfloat16* __restrict__ w2t, float* __restrict__ beff) {
  const int n = blockIdx.x * 8 + (threadIdx.x >> 5);
  const int f = threadIdx.x & 31;
  const float* wr = W2 + (size_t)n * TFD;
  float s = 0.f;
  #pragma unroll 8
  for (int t = 0; t < TT; ++t) s += wr[t * FF + f] * weight[t * FF + f];
  w2t[(size_t)f * THD + n] = __float2bfloat16(s);
  if (blockIdx.x == 0 && threadIdx.x < FF) {
    float sb = bias[f];
    for (int t = 0; t < TT; ++t) sb += b2[t * FF + f] * weight[t * FF + f];
    beff[f] = sb;
  }
}

// ---------------- main fused GEMM ----------------
// r18 = r16 verbatim (best verified: 593.7us total, gemm ~510-518us,
// MfmaUtil 51-52.5%). r17's 32x32-MFMA port regressed (bank conflicts
// 1.1e6 -> 3.5e7 [layout model falsified without disasm access] + 8
// dependent back-to-back MFMA pairs per iter) -> reverted.
// Structure: 256b x 256n tile, 8 waves (2 mq x 4 bq), 1 block/CU, BK=32,
// 8 x 16KB W LDS buffers staged 3 ahead (paired-row 128B rows + XOR chunk
// swizzle = conflict-free), X in regs via parity xfA/xfB (4 coalesced 1KB
// loads from fragment-linear xsf, refill-just-consumed with tile v+2),
// flattened 256-iter v-loop (v = s*64+t), barrier every 2nd v, setprio
// around MFMA clusters, per-s GEMM2 epilogue on the matrix pipe.
// vmcnt ledger (FIFO per wave; S=2, R=4 loads): end-of-v drain-to-6
// leaves {S(v+3), R(v+2)}. Predicates: stage v<=252, refill v<=253,
// VMW: v<=252 -> 6, v==253 -> 4, else 0. Prologue S0,rA,S1,rB,S2 = 14
// -> VMW(8) drains S0+rA. Epilogue VMEM loads append behind {S,R} in the
// FIFO; later VMW(6) drains them conservatively. Buffer safety: writes
// (v+3)&7 vs window reads {v,v+1}&7 distance 2..4 mod 8.

__device__ inline void stage_w(char* buf, const __hip_bfloat16* __restrict__ w1t,
                               int n0, int k0, int wid, int l) {
  const int sub = l >> 3;
  const int c   = (l & 7) ^ sub;             // inverse chunk swizzle
  const int h   = c >> 2, kc = c & 3;
  const int r0  = wid * 8 + sub;             // lds row (128B rows, 2 logical rows each)
  const __hip_bfloat16* gw0 = w1t + (size_t)(n0 + 2 * r0 + h) * TFD + k0 + kc * 8;
  const __hip_bfloat16* gw1 = w1t + (size_t)(n0 + 128 + 2 * r0 + h) * TFD + k0 + kc * 8;
  char* lx = buf + wid * 1024;               // wave-uniform base; HW adds lane*16
  gload_lds16(gw0, lx);
  gload_lds16(gw1, lx + 8192);
}

__device__ __forceinline__ void k_iter(char* lds, int v, int strip,
    const char* __restrict__ xbase, const __hip_bfloat16* __restrict__ w1t,
    f32x4 (&acc)[8][4], bf16x8 (&xfu)[4],
    int wbase, int wid, int l, bool do_bar) {
  if (v <= 252) {
    const int vs = v + 3;
    stage_w(lds + (size_t)(vs & 7) * 16384, w1t,
            strip * 1024 + (vs >> 6) * 256, (vs & 63) * 32, wid, l);
  }
  SCHED;
  const char* buf = lds + (size_t)(v & 7) * 16384;
  bf16x8 w0  = *(const bf16x8*)(buf + wbase);
  bf16x8 w1f = *(const bf16x8*)(buf + wbase + 1024);
  #pragma unroll
  for (int g = 0; g < 4; ++g) {
    bf16x8 nw0, nw1;
    if (g < 3) {
      nw0 = *(const bf16x8*)(buf + wbase + (2 * g + 2) * 1024);
      nw1 = *(const bf16x8*)(buf + wbase + (2 * g + 3) * 1024);
    }
    __builtin_amdgcn_s_setprio(1);
    #pragma unroll
    for (int bi = 0; bi < 4; ++bi)
      acc[2 * g][bi] = __builtin_amdgcn_mfma_f32_16x16x32_bf16(w0, xfu[bi], acc[2 * g][bi], 0, 0, 0);
    #pragma unroll
    for (int bi = 0; bi < 4; ++bi)
      acc[2 * g + 1][bi] = __builtin_amdgcn_mfma_f32_16x16x32_bf16(w1f, xfu[bi], acc[2 * g + 1][bi], 0, 0, 0);
    __builtin_amdgcn_s_setprio(0);
    if (g < 3) { w0 = nw0; w1f = nw1; }
  }
  if (v <= 253) {   // refill the JUST-CONSUMED set with X tile (v+2) (cyclical over s)
    const int u = (v + 2) & 63;
    #pragma unroll
    for (int bi = 0; bi < 4; ++bi)
      xfu[bi] = *(const bf16x8*)(xbase + (u * 4 + bi) * 1024);
  }
  SCHED;
  if (v <= 252)      { VMW(6); }
  else if (v == 253) { VMW(4); }
  else               { VMW(0); }
  SCHED;
  if (do_bar) {
    __builtin_amdgcn_s_barrier(); SCHED;
  }
}

__global__ __launch_bounds__(512, 2) void gemm_fused(
    const __hip_bfloat16* __restrict__ xsf,   // fragment-linear X
    const __hip_bfloat16* __restrict__ w1t,   // [THD][TFD]
    const float* __restrict__ b1,             // [THD]
    const __hip_bfloat16* __restrict__ w2t,   // [FF][THD] bf16
    float* __restrict__ partial)              // [8][BATCH][FF]
{
  __shared__ __align__(16) char lds[131072];  // 8 x 16KB W buffers
  const int tid = threadIdx.x;
  const int wid = tid >> 6, l = tid & 63;
  const int mq = wid >> 2, bq = wid & 3;      // wave: n_w1-half (2) x batch-quarter (4)
  const int lo = l & 15, hi = l >> 4;
  const int rl = lo >> 1;
  const int cofs = (((((lo & 1) << 2) | hi) ^ rl) << 4);
  const int strip = blockIdx.x & 7;           // strip == XCD -> W slice L2-resident
  const int bt = blockIdx.x >> 3;
  const int b0 = bt * 256;

  const int wbase = ((mq << 6) + rl) * 128 + cofs;              // + mi*1024
  const char* xbase = (const char*)xsf + ((size_t)(bt * 4 + bq) * 16384 + l) * 16;

  f32x4 acc2[2][4];                           // emb^T partial: [f-frag][batch-frag]
  #pragma unroll
  for (int fi = 0; fi < 2; ++fi)
    #pragma unroll
    for (int bi = 0; bi < 4; ++bi) { f32x4 z = {0.f,0.f,0.f,0.f}; acc2[fi][bi] = z; }

  f32x4 acc[8][4];
  #pragma unroll
  for (int mi = 0; mi < 8; ++mi)
    #pragma unroll
    for (int bi = 0; bi < 4; ++bi) { f32x4 z = {0.f,0.f,0.f,0.f}; acc[mi][bi] = z; }

  bf16x8 xfA[4], xfB[4];
  // ---- prologue (ONCE): S0, rA<-t0, S1, rB<-t1, S2; VMW(8) drains S0+rA ----
  stage_w(lds, w1t, strip * 1024, 0, wid, l);
  SCHED;
  #pragma unroll
  for (int bi = 0; bi < 4; ++bi) xfA[bi] = *(const bf16x8*)(xbase + (0 * 4 + bi) * 1024);
  SCHED;
  stage_w(lds + 16384, w1t, strip * 1024, 32, wid, l);
  SCHED;
  #pragma unroll
  for (int bi = 0; bi < 4; ++bi) xfB[bi] = *(const bf16x8*)(xbase + (1 * 4 + bi) * 1024);
  SCHED;
  stage_w(lds + 32768, w1t, strip * 1024, 64, wid, l);
  SCHED;
  VMW(8); SCHED;
  __builtin_amdgcn_s_barrier(); SCHED;

  for (int vv = 0; vv < 256; vv += 2) {
    k_iter(lds, vv,     strip, xbase, w1t, acc, xfA, wbase, wid, l, false);
    k_iter(lds, vv + 1, strip, xbase, w1t, acc, xfB, wbase, wid, l, true);

    if ((vv & 63) == 62) {
      // ---- epilogue for s = vv>>6: bias+relu+pack, GEMM2 on matrix pipe ----
      const int n0e = strip * 1024 + (vv >> 6) * 256;
      #pragma unroll
      for (int mi = 0; mi < 8; ++mi) {
        const int nbase = n0e + (mq << 7) + (mi << 4);
        const float4 b1v = *(const float4*)(b1 + nbase + (hi << 2));
        bf16x4 p[4];
        #pragma unroll
        for (int bi = 0; bi < 4; ++bi) {
          bf16x4 pk;
          #pragma unroll
          for (int j = 0; j < 4; ++j) {
            float v = acc[mi][bi][j] + ((const float*)&b1v)[j];
            v = v > 0.f ? v : 0.f;
            pk[j] = f32_to_bf16_bits(v);
          }
          p[bi] = pk;
        }
        bf16x4 a2[2];
        #pragma unroll
        for (int fi = 0; fi < 2; ++fi)
          a2[fi] = *(const bf16x4*)(w2t + (size_t)(fi * 16 + lo) * THD + nbase + (hi << 2));
        #pragma unroll
        for (int fi = 0; fi < 2; ++fi)
          #pragma unroll
          for (int bi = 0; bi < 4; ++bi)
            acc2[fi][bi] = mfma16x16x16_bf16(a2[fi], p[bi], acc2[fi][bi]);
        // reset this mi's accumulators for the next s
        #pragma unroll
        for (int bi = 0; bi < 4; ++bi) { f32x4 z = {0.f,0.f,0.f,0.f}; acc[mi][bi] = z; }
      }
    }
  }

  // ---- merge the two mq-halves via LDS, then store ----
  float* sm = (float*)lds;                    // [256][32] f32 (32KB; buffers dead)
  __syncthreads();                            // all K-loop LDS reads retired
  if (mq == 1) {
    #pragma unroll
    for (int fi = 0; fi < 2; ++fi)
      #pragma unroll
      for (int bi = 0; bi < 4; ++bi)
        *(f32x4*)(sm + ((bq << 6) + (bi << 4) + lo) * 32 + fi * 16 + (hi << 2)) = acc2[fi][bi];
  }
  __syncthreads();
  if (mq == 0) {
    #pragma unroll
    for (int fi = 0; fi < 2; ++fi)
      #pragma unroll
      for (int bi = 0; bi < 4; ++bi) {
        f32x4 other = *(const f32x4*)(sm + ((bq << 6) + (bi << 4) + lo) * 32 + fi * 16 + (hi << 2));
        f32x4 v = acc2[fi][bi] + other;
        *(f32x4*)(partial + ((size_t)strip * BATCH + b0 + (bq << 6) + (bi << 4) + lo) * FF + fi * 16 + (hi << 2)) = v;
      }
  }
}

// out[b][f] = beff[f] + sum_c partial[c][b][f]
__global__ void reduce_partial(const float* __restrict__ partial, const float* __restrict__ beff,
                               float* __restrict__ out) {
  const int idx = blockIdx.x * 256 + threadIdx.x;
  float s = beff[idx & 31];
  #pragma unroll
  for (int c = 0; c < 8; ++c) s += partial[(size_t)c * BATCH * FF + idx];
  out[idx] = s;
}

// ---------------- launch ----------------

extern "C" void kernel_launch(void* const* d_in, const int* in_sizes, int n_in,
                              void* d_out, int out_size, void* d_ws, size_t ws_size,
                              hipStream_t stream) {
  const float* x      = (const float*)d_in[0];
  const float* W1     = (const float*)d_in[1];
  const float* b1     = (const float*)d_in[2];
  const float* W2     = (const float*)d_in[3];
  const float* b2     = (const float*)d_in[4];
  const float* weight = (const float*)d_in[5];
  const float* bias   = (const float*)d_in[6];
  const int*   sidx   = (const int*)d_in[7];

  char* ws = (char*)d_ws;
  // ws layout (bytes):
  //   xsf     [16384][2048] bf16 (frag-linear) : 0 .. 67108864
  //   w1t     [8192][2048]  bf16 :  67108864 .. 100663296
  //   w2t     [32][8192]    bf16 : 100663296 .. 101187584
  //   beff    [32]          f32  : 101187584 .. 101187712
  //   partial [8][16384][32] f32 : 101188608 .. 117965824
  __hip_bfloat16* xsf  = (__hip_bfloat16*)ws;
  __hip_bfloat16* w1t  = (__hip_bfloat16*)(ws + 67108864);
  __hip_bfloat16* w2t  = (__hip_bfloat16*)(ws + 100663296);
  float*          beff = (float*)(ws + 101187584);
  float*          part = (float*)(ws + 101188608);

  hipLaunchKernelGGL(gather_cast_frag, dim3(1024), dim3(256), 0, stream, x, sidx, xsf);
  hipLaunchKernelGGL(transpose_w1, dim3(32, 128), dim3(256), 0, stream, W1, w1t);
  hipLaunchKernelGGL(make_w2eff,   dim3(1024),    dim3(256), 0, stream, W2, b2, weight, bias, w2t, beff);
  hipLaunchKernelGGL(gemm_fused,   dim3(512),     dim3(512), 0, stream, xsf, w1t, b1, w2t, part);
  hipLaunchKernelGGL(reduce_partial, dim3(2048),  dim3(256), 0, stream, part, beff, (float*)d_out);
}